// Round 1
// baseline (1412.410 us; speedup 1.0000x reference)
//
#include <hip/hip_runtime.h>
#include <math.h>

// JointAttention: B=64, N+1=16, T=256, H=128, TEMP=1
// out  [B,T,H]        (2,097,152 f32)
// A    [B,T,16,T]     (268,435,456 f32)
// S_norm [B]          (64 f32)
//
// Plan: fp32 everywhere (no fp32 MFMA on CDNA4; bf16-split MFMA in later rounds).
//  K1 proj (x3): q/k/v = x @ W^T + b  -> workspace
//  K2 passA: online max m / sumexp l per (b,t) over all 4096 keys (causal mask s>t),
//            plus per-block partial sum of S^2 (pre-mask) for S_norm.
//  K3 passB: recompute scores, A = exp(s-m)/l (0 if masked) -> d_out, out += A*v.
//  K4 finalize: S_norm[b] = sqrt(sum of 4 partials).

constexpr int BB   = 64;
constexpr int NN1  = 16;          // N+1
constexpr int TT   = 256;
constexpr int HH   = 128;
constexpr int KEYS = NN1 * TT;    // 4096
constexpr int LDP  = 132;         // padded LDS row stride (floats); 528B, 16B-aligned

__device__ __forceinline__ float4 ld4(const float* p) {
  return *reinterpret_cast<const float4*>(p);
}
__device__ __forceinline__ void st4(float* p, float4 v) {
  *reinterpret_cast<float4*>(p) = v;
}

// ---------------- projection: y[r][j] = sum_h x[r][h]*W[j][h] + b[j] ----------------
// mode 0: rows = B*T from node.  mode 1: rows = B*16*T from kv = [node, neigh].
// tile: 128 rows x 128 cols, 256 threads, 8x8 micro-tile. VALU-bound.
__global__ __launch_bounds__(256) void proj_kernel(
    const float* __restrict__ node, const float* __restrict__ neigh,
    const float* __restrict__ W, const float* __restrict__ bias,
    float* __restrict__ y, int mode)
{
  __shared__ float xs[128 * LDP];
  __shared__ float Ws[128 * LDP];
  const int tid = threadIdx.x;
  const long r0 = (long)blockIdx.x * 128;

  // stage W (128x128) and x tile (128 rows), float4, coalesced; b128 LDS writes
  #pragma unroll
  for (int i = 0; i < 16; ++i) {
    int slot = tid + 256 * i;           // 0..4095
    int row = slot >> 5, hh = (slot & 31) << 2;
    st4(&Ws[row * LDP + hh], ld4(W + row * HH + hh));
  }
  for (int i = 0; i < 16; ++i) {
    int slot = tid + 256 * i;
    int row = slot >> 5, hh = (slot & 31) << 2;
    long r = r0 + row;
    const float* src;
    if (mode == 0) {
      src = node + r * HH;
    } else {
      long bb = r >> 12;                       // 4096 rows per batch
      int  n  = (int)((r >> 8) & 15);
      int  t  = (int)(r & 255);
      src = (n == 0) ? (node + (bb * TT + t) * HH)
                     : (neigh + ((bb * 15 + (n - 1)) * (long)TT + t) * HH);
    }
    st4(&xs[row * LDP + hh], ld4(src + hh));
  }
  __syncthreads();

  const int tx = tid & 15, ty = tid >> 4;  // cols j = tx+16*jj ; rows r = ty*8+rr
  float bj[8];
  #pragma unroll
  for (int jj = 0; jj < 8; ++jj) bj[jj] = bias[tx + 16 * jj];
  float acc[8][8];
  #pragma unroll
  for (int rr = 0; rr < 8; ++rr)
    #pragma unroll
    for (int jj = 0; jj < 8; ++jj) acc[rr][jj] = bj[jj];

  for (int h = 0; h < HH; h += 4) {
    float4 xv[8], wv[8];
    #pragma unroll
    for (int rr = 0; rr < 8; ++rr) xv[rr] = ld4(&xs[(ty * 8 + rr) * LDP + h]);
    #pragma unroll
    for (int jj = 0; jj < 8; ++jj) wv[jj] = ld4(&Ws[(tx + 16 * jj) * LDP + h]);
    #pragma unroll
    for (int rr = 0; rr < 8; ++rr)
      #pragma unroll
      for (int jj = 0; jj < 8; ++jj) {
        acc[rr][jj] = fmaf(xv[rr].x, wv[jj].x, acc[rr][jj]);
        acc[rr][jj] = fmaf(xv[rr].y, wv[jj].y, acc[rr][jj]);
        acc[rr][jj] = fmaf(xv[rr].z, wv[jj].z, acc[rr][jj]);
        acc[rr][jj] = fmaf(xv[rr].w, wv[jj].w, acc[rr][jj]);
      }
  }

  #pragma unroll
  for (int rr = 0; rr < 8; ++rr) {
    long r = r0 + ty * 8 + rr;
    #pragma unroll
    for (int jj = 0; jj < 8; ++jj)
      y[r * HH + tx + 16 * jj] = acc[rr][jj];
  }
}

// ---------------- pass A: online softmax stats + ssq ----------------
// block: (b, 64-query tile). keys iterated in 128-tiles. 4x8 micro-tile.
__global__ __launch_bounds__(256) void passA_kernel(
    const float* __restrict__ q_ws, const float* __restrict__ k_ws,
    float* __restrict__ m_ws, float* __restrict__ l_ws,
    float* __restrict__ ssq_part)
{
  __shared__ float qs[64 * LDP];
  __shared__ float ks[128 * LDP];
  const int tid = threadIdx.x;
  const int b  = blockIdx.x >> 2;
  const int t0 = (blockIdx.x & 3) * 64;

  #pragma unroll
  for (int i = 0; i < 8; ++i) {
    int slot = tid + 256 * i;
    int row = slot >> 5, hh = (slot & 31) << 2;
    st4(&qs[row * LDP + hh], ld4(q_ws + ((long)(b * TT + t0 + row)) * HH + hh));
  }

  const int tx = tid & 15, ty = tid >> 4;  // keys tx+16*jj, rows ty*4+rr
  float mrow[4] = {-INFINITY, -INFINITY, -INFINITY, -INFINITY};
  float lrow[4] = {0.f, 0.f, 0.f, 0.f};
  float ssq = 0.f;

  for (int kt = 0; kt < KEYS / 128; ++kt) {
    const int kb = kt * 128;
    __syncthreads();
    #pragma unroll
    for (int i = 0; i < 16; ++i) {
      int slot = tid + 256 * i;
      int row = slot >> 5, hh = (slot & 31) << 2;
      st4(&ks[row * LDP + hh],
          ld4(k_ws + ((long)b * KEYS + kb + row) * HH + hh));
    }
    __syncthreads();

    float sc[4][8];
    #pragma unroll
    for (int rr = 0; rr < 4; ++rr)
      #pragma unroll
      for (int jj = 0; jj < 8; ++jj) sc[rr][jj] = 0.f;

    for (int h = 0; h < HH; h += 4) {
      float4 qv[4], kv[8];
      #pragma unroll
      for (int rr = 0; rr < 4; ++rr) qv[rr] = ld4(&qs[(ty * 4 + rr) * LDP + h]);
      #pragma unroll
      for (int jj = 0; jj < 8; ++jj) kv[jj] = ld4(&ks[(tx + 16 * jj) * LDP + h]);
      #pragma unroll
      for (int rr = 0; rr < 4; ++rr)
        #pragma unroll
        for (int jj = 0; jj < 8; ++jj) {
          sc[rr][jj] = fmaf(qv[rr].x, kv[jj].x, sc[rr][jj]);
          sc[rr][jj] = fmaf(qv[rr].y, kv[jj].y, sc[rr][jj]);
          sc[rr][jj] = fmaf(qv[rr].z, kv[jj].z, sc[rr][jj]);
          sc[rr][jj] = fmaf(qv[rr].w, kv[jj].w, sc[rr][jj]);
        }
    }

    const int sbase = kb & (TT - 1);
    #pragma unroll
    for (int rr = 0; rr < 4; ++rr) {
      const int t = t0 + ty * 4 + rr;
      float scm[8], mx = -INFINITY;
      #pragma unroll
      for (int jj = 0; jj < 8; ++jj) {
        float s_ = sc[rr][jj];
        ssq = fmaf(s_, s_, ssq);                         // pre-mask norm
        scm[jj] = (sbase + tx + 16 * jj <= t) ? s_ : -INFINITY;
        mx = fmaxf(mx, scm[jj]);
      }
      if (mx > mrow[rr]) { lrow[rr] *= __expf(mrow[rr] - mx); mrow[rr] = mx; }
      if (mrow[rr] > -INFINITY) {
        #pragma unroll
        for (int jj = 0; jj < 8; ++jj) lrow[rr] += __expf(scm[jj] - mrow[rr]);
      }
    }
  }

  // reduce m/l across the 16 tx threads per row (reuse ks)
  __syncthreads();
  float* mred = ks;             // [64][16]
  float* lred = ks + 64 * 16;   // [64][16]
  #pragma unroll
  for (int rr = 0; rr < 4; ++rr) {
    mred[(ty * 4 + rr) * 16 + tx] = mrow[rr];
    lred[(ty * 4 + rr) * 16 + tx] = lrow[rr];
  }
  __syncthreads();
  if (tid < 64) {
    float m = -INFINITY;
    for (int i = 0; i < 16; ++i) m = fmaxf(m, mred[tid * 16 + i]);
    float l = 0.f;
    for (int i = 0; i < 16; ++i) {
      float mi = mred[tid * 16 + i];
      if (mi > -INFINITY) l += lred[tid * 16 + i] * __expf(mi - m);
    }
    m_ws[b * TT + t0 + tid] = m;
    l_ws[b * TT + t0 + tid] = l;
  }

  // ssq: wave shuffle reduce, then 4-wave combine via qs[0..3]
  float s = ssq;
  #pragma unroll
  for (int off = 32; off > 0; off >>= 1) s += __shfl_down(s, off);
  if ((tid & 63) == 0) qs[tid >> 6] = s;
  __syncthreads();
  if (tid == 0) ssq_part[blockIdx.x] = qs[0] + qs[1] + qs[2] + qs[3];
}

// ---------------- pass B: recompute scores, write A, out = A*V ----------------
__global__ __launch_bounds__(256) void passB_kernel(
    const float* __restrict__ q_ws, const float* __restrict__ k_ws,
    const float* __restrict__ v_ws, const float* __restrict__ m_ws,
    const float* __restrict__ l_ws, float* __restrict__ A_out,
    float* __restrict__ out)
{
  __shared__ float qs[64 * LDP];
  __shared__ float ks[128 * LDP];   // k tile, then v tile
  __shared__ float As[64 * LDP];
  const int tid = threadIdx.x;
  const int b  = blockIdx.x >> 2;
  const int t0 = (blockIdx.x & 3) * 64;

  #pragma unroll
  for (int i = 0; i < 8; ++i) {
    int slot = tid + 256 * i;
    int row = slot >> 5, hh = (slot & 31) << 2;
    st4(&qs[row * LDP + hh], ld4(q_ws + ((long)(b * TT + t0 + row)) * HH + hh));
  }

  const int tx = tid & 15, ty = tid >> 4;
  float mrow[4], rinv[4];
  #pragma unroll
  for (int rr = 0; rr < 4; ++rr) {
    int t = t0 + ty * 4 + rr;
    mrow[rr] = m_ws[b * TT + t];
    rinv[rr] = 1.0f / l_ws[b * TT + t];
  }
  float oacc[4][8];
  #pragma unroll
  for (int rr = 0; rr < 4; ++rr)
    #pragma unroll
    for (int jj = 0; jj < 8; ++jj) oacc[rr][jj] = 0.f;

  for (int kt = 0; kt < KEYS / 128; ++kt) {
    const int kb = kt * 128;
    __syncthreads();  // protect ks (prev AV reads) before restaging
    #pragma unroll
    for (int i = 0; i < 16; ++i) {
      int slot = tid + 256 * i;
      int row = slot >> 5, hh = (slot & 31) << 2;
      st4(&ks[row * LDP + hh],
          ld4(k_ws + ((long)b * KEYS + kb + row) * HH + hh));
    }
    __syncthreads();

    float sc[4][8];
    #pragma unroll
    for (int rr = 0; rr < 4; ++rr)
      #pragma unroll
      for (int jj = 0; jj < 8; ++jj) sc[rr][jj] = 0.f;

    for (int h = 0; h < HH; h += 4) {
      float4 qv[4], kv[8];
      #pragma unroll
      for (int rr = 0; rr < 4; ++rr) qv[rr] = ld4(&qs[(ty * 4 + rr) * LDP + h]);
      #pragma unroll
      for (int jj = 0; jj < 8; ++jj) kv[jj] = ld4(&ks[(tx + 16 * jj) * LDP + h]);
      #pragma unroll
      for (int rr = 0; rr < 4; ++rr)
        #pragma unroll
        for (int jj = 0; jj < 8; ++jj) {
          sc[rr][jj] = fmaf(qv[rr].x, kv[jj].x, sc[rr][jj]);
          sc[rr][jj] = fmaf(qv[rr].y, kv[jj].y, sc[rr][jj]);
          sc[rr][jj] = fmaf(qv[rr].z, kv[jj].z, sc[rr][jj]);
          sc[rr][jj] = fmaf(qv[rr].w, kv[jj].w, sc[rr][jj]);
        }
    }

    const int sbase = kb & (TT - 1);
    #pragma unroll
    for (int rr = 0; rr < 4; ++rr) {
      const int t = t0 + ty * 4 + rr;
      const long abase = ((long)(b * TT + t)) * KEYS + kb;
      #pragma unroll
      for (int jj = 0; jj < 8; ++jj) {
        int kl = tx + 16 * jj;
        float a = (sbase + kl <= t) ? __expf(sc[rr][jj] - mrow[rr]) * rinv[rr] : 0.f;
        A_out[abase + kl] = a;
        As[(ty * 4 + rr) * LDP + kl] = a;
      }
    }
    __syncthreads();  // As visible; done reading ks (k)

    // stage v tile (row-major, same as k)
    #pragma unroll
    for (int i = 0; i < 16; ++i) {
      int slot = tid + 256 * i;
      int row = slot >> 5, hh = (slot & 31) << 2;
      st4(&ks[row * LDP + hh],
          ld4(v_ws + ((long)b * KEYS + kb + row) * HH + hh));
    }
    __syncthreads();

    // oacc[rr][jj] (h = tx+16*jj) += sum_k As[r][k] * v[k][h]
    for (int k = 0; k < 128; k += 4) {
      float4 a4[4];
      #pragma unroll
      for (int rr = 0; rr < 4; ++rr) a4[rr] = ld4(&As[(ty * 4 + rr) * LDP + k]);
      #pragma unroll
      for (int kk = 0; kk < 4; ++kk) {
        float vv[8];
        #pragma unroll
        for (int jj = 0; jj < 8; ++jj) vv[jj] = ks[(k + kk) * LDP + tx + 16 * jj];
        #pragma unroll
        for (int rr = 0; rr < 4; ++rr) {
          float a = ((const float*)&a4[rr])[kk];
          #pragma unroll
          for (int jj = 0; jj < 8; ++jj)
            oacc[rr][jj] = fmaf(a, vv[jj], oacc[rr][jj]);
        }
      }
    }
  }

  #pragma unroll
  for (int rr = 0; rr < 4; ++rr) {
    long r = (long)(b * TT + t0 + ty * 4 + rr);
    #pragma unroll
    for (int jj = 0; jj < 8; ++jj)
      out[r * HH + tx + 16 * jj] = oacc[rr][jj];
  }
}

// ---------------- finalize S_norm ----------------
__global__ void finalize_kernel(const float* __restrict__ ssq_part,
                                float* __restrict__ S_norm)
{
  int b = threadIdx.x;
  if (b < BB) {
    float s = ssq_part[b * 4] + ssq_part[b * 4 + 1] +
              ssq_part[b * 4 + 2] + ssq_part[b * 4 + 3];
    S_norm[b] = sqrtf(s);
  }
}

extern "C" void kernel_launch(void* const* d_in, const int* in_sizes, int n_in,
                              void* d_out, int out_size, void* d_ws, size_t ws_size,
                              hipStream_t stream)
{
  const float* node  = (const float*)d_in[0];   // [B,T,H]
  const float* neigh = (const float*)d_in[1];   // [B,15,T,H]
  // d_in[2] = neighbors_number (15, fixed), d_in[3] = attn_mask (causal, hardcoded)
  const float* Wq = (const float*)d_in[4];
  const float* bq = (const float*)d_in[5];
  const float* Wk = (const float*)d_in[6];
  const float* bk = (const float*)d_in[7];
  const float* Wv = (const float*)d_in[8];
  const float* bv = (const float*)d_in[9];

  float* out    = (float*)d_out;                      // [B,T,H]
  float* A_out  = out + (long)BB * TT * HH;           // [B,T,16,T]
  float* S_norm = A_out + (long)BB * TT * KEYS;       // [B]

  float* ws   = (float*)d_ws;
  float* q_ws = ws;                                   // B*T*H
  float* k_ws = q_ws + (long)BB * TT * HH;            // B*4096*128
  float* v_ws = k_ws + (long)BB * KEYS * HH;          // B*4096*128
  float* m_ws = v_ws + (long)BB * KEYS * HH;          // B*T
  float* l_ws = m_ws + BB * TT;                       // B*T
  float* ssq_part = l_ws + BB * TT;                   // 256

  hipLaunchKernelGGL(proj_kernel, dim3(BB * TT / 128), dim3(256), 0, stream,
                     node, neigh, Wq, bq, q_ws, 0);
  hipLaunchKernelGGL(proj_kernel, dim3(BB * KEYS / 128), dim3(256), 0, stream,
                     node, neigh, Wk, bk, k_ws, 1);
  hipLaunchKernelGGL(proj_kernel, dim3(BB * KEYS / 128), dim3(256), 0, stream,
                     node, neigh, Wv, bv, v_ws, 1);
  hipLaunchKernelGGL(passA_kernel, dim3(BB * 4), dim3(256), 0, stream,
                     q_ws, k_ws, m_ws, l_ws, ssq_part);
  hipLaunchKernelGGL(passB_kernel, dim3(BB * 4), dim3(256), 0, stream,
                     q_ws, k_ws, v_ws, m_ws, l_ws, A_out, out);
  hipLaunchKernelGGL(finalize_kernel, dim3(1), dim3(64), 0, stream,
                     ssq_part, S_norm);
}

// Round 2
// 673.431 us; speedup vs baseline: 2.0973x; 2.0973x over previous
//
#include <hip/hip_runtime.h>
#include <math.h>

// JointAttention B=64, N+1=16, T=256, H=128, TEMP=1
// R2: MFMA attention. Split-bf16 (hi+lo) QK^T via 3x mfma_f32_32x32x16_bf16;
// single-bf16 A*V. Projections stay fp32 VALU but emit MFMA-ready formats:
//   qhl/khl: u32 = bf16(hi) | bf16(lo)<<16   [row][h]
//   v_t:     bf16, TRANSPOSED [b][h][key]
// passA: online m/l per (b,t) + ssq (pre-mask), key-split x4 for occupancy.
// passB: recompute S, write A (f32), PV accumulate; key-split x2 + O-reduce.

constexpr int BB   = 64;
constexpr int TT   = 256;
constexpr int HH   = 128;
constexpr int KEYS = 4096;
constexpr int LDP  = 132;   // fp32 proj LDS pad
constexpr int LDK  = 136;   // bf16 K-tile pad (272B rows, 16B aligned)
constexpr int LDV  = 72;    // bf16 Vt/As pad (144B rows, 16B aligned)

typedef __attribute__((ext_vector_type(8)))  __bf16 bf16x8;
typedef __attribute__((ext_vector_type(16))) float  f32x16;

union BF8 { unsigned u[4]; bf16x8 v; };

__device__ __forceinline__ float4 ld4(const float* p) {
  return *reinterpret_cast<const float4*>(p);
}
__device__ __forceinline__ void st4(float* p, float4 v) {
  *reinterpret_cast<float4*>(p) = v;
}
__device__ __forceinline__ unsigned short f2bf(float x) {
  unsigned u = __float_as_uint(x);
  return (unsigned short)((u + 0x7fffu + ((u >> 16) & 1u)) >> 16);
}
__device__ __forceinline__ unsigned packhl(float x) {
  unsigned short hi = f2bf(x);
  float hif = __uint_as_float(((unsigned)hi) << 16);
  unsigned short lo = f2bf(x - hif);
  return (unsigned)hi | (((unsigned)lo) << 16);
}
__device__ __forceinline__ f32x16 zero16() {
  f32x16 z;
  #pragma unroll
  for (int i = 0; i < 16; ++i) z[i] = 0.f;
  return z;
}
__device__ __forceinline__ f32x16 mfma3(bf16x8 ahi, bf16x8 alo,
                                        bf16x8 bhi, bf16x8 blo, f32x16 c) {
  c = __builtin_amdgcn_mfma_f32_32x32x16_bf16(ahi, bhi, c, 0, 0, 0);
  c = __builtin_amdgcn_mfma_f32_32x32x16_bf16(ahi, blo, c, 0, 0, 0);
  c = __builtin_amdgcn_mfma_f32_32x32x16_bf16(alo, bhi, c, 0, 0, 0);
  return c;
}

// ---------------- fp32 projection core (same as R1), templated epilogue ----
// mode 0: rows = B*T (node); mode 1: rows = B*16*T (kv = [node, neigh]).
__device__ __forceinline__ void proj_core(
    const float* __restrict__ node, const float* __restrict__ neigh,
    const float* __restrict__ W, const float* __restrict__ bias,
    int mode, float* xs, float* Ws, float acc[8][8])
{
  const int tid = threadIdx.x;
  const long r0 = (long)blockIdx.x * 128;
  #pragma unroll
  for (int i = 0; i < 16; ++i) {
    int slot = tid + 256 * i;
    int row = slot >> 5, hh = (slot & 31) << 2;
    st4(&Ws[row * LDP + hh], ld4(W + row * HH + hh));
  }
  for (int i = 0; i < 16; ++i) {
    int slot = tid + 256 * i;
    int row = slot >> 5, hh = (slot & 31) << 2;
    long r = r0 + row;
    const float* src;
    if (mode == 0) {
      src = node + r * HH;
    } else {
      long bb = r >> 12;
      int  n  = (int)((r >> 8) & 15);
      int  t  = (int)(r & 255);
      src = (n == 0) ? (node + (bb * TT + t) * HH)
                     : (neigh + ((bb * 15 + (n - 1)) * (long)TT + t) * HH);
    }
    st4(&xs[row * LDP + hh], ld4(src + hh));
  }
  __syncthreads();

  const int tx = tid & 15, ty = tid >> 4;
  float bj[8];
  #pragma unroll
  for (int jj = 0; jj < 8; ++jj) bj[jj] = bias[tx + 16 * jj];
  #pragma unroll
  for (int rr = 0; rr < 8; ++rr)
    #pragma unroll
    for (int jj = 0; jj < 8; ++jj) acc[rr][jj] = bj[jj];

  for (int h = 0; h < HH; h += 4) {
    float4 xv[8], wv[8];
    #pragma unroll
    for (int rr = 0; rr < 8; ++rr) xv[rr] = ld4(&xs[(ty * 8 + rr) * LDP + h]);
    #pragma unroll
    for (int jj = 0; jj < 8; ++jj) wv[jj] = ld4(&Ws[(tx + 16 * jj) * LDP + h]);
    #pragma unroll
    for (int rr = 0; rr < 8; ++rr)
      #pragma unroll
      for (int jj = 0; jj < 8; ++jj) {
        acc[rr][jj] = fmaf(xv[rr].x, wv[jj].x, acc[rr][jj]);
        acc[rr][jj] = fmaf(xv[rr].y, wv[jj].y, acc[rr][jj]);
        acc[rr][jj] = fmaf(xv[rr].z, wv[jj].z, acc[rr][jj]);
        acc[rr][jj] = fmaf(xv[rr].w, wv[jj].w, acc[rr][jj]);
      }
  }
}

// q/k projection -> packed split-bf16 u32 [row][h]
__global__ __launch_bounds__(256) void proj_pack_kernel(
    const float* __restrict__ node, const float* __restrict__ neigh,
    const float* __restrict__ W, const float* __restrict__ bias,
    unsigned* __restrict__ y, int mode)
{
  __shared__ float xs[128 * LDP];
  __shared__ float Ws[128 * LDP];
  float acc[8][8];
  proj_core(node, neigh, W, bias, mode, xs, Ws, acc);
  const int tx = threadIdx.x & 15, ty = threadIdx.x >> 4;
  const long r0 = (long)blockIdx.x * 128;
  #pragma unroll
  for (int rr = 0; rr < 8; ++rr) {
    long r = r0 + ty * 8 + rr;
    #pragma unroll
    for (int jj = 0; jj < 8; ++jj)
      y[r * HH + tx + 16 * jj] = packhl(acc[rr][jj]);
  }
}

// v projection -> transposed bf16 v_t[b][h][key]
__global__ __launch_bounds__(256) void proj_vt_kernel(
    const float* __restrict__ node, const float* __restrict__ neigh,
    const float* __restrict__ W, const float* __restrict__ bias,
    unsigned short* __restrict__ v_t)
{
  __shared__ float xs[128 * LDP];
  __shared__ float Ws[128 * LDP];
  float acc[8][8];
  proj_core(node, neigh, W, bias, 1, xs, Ws, acc);
  const int tx = threadIdx.x & 15, ty = threadIdx.x >> 4;
  const long r0 = (long)blockIdx.x * 128;
  const int b = (int)(r0 >> 12);
  const int key0 = (int)(r0 & 4095) + ty * 8;   // 8 consecutive keys (rr)
  #pragma unroll
  for (int jj = 0; jj < 8; ++jj) {
    int j = tx + 16 * jj;
    uint4 u;
    u.x = (unsigned)f2bf(acc[0][jj]) | (((unsigned)f2bf(acc[1][jj])) << 16);
    u.y = (unsigned)f2bf(acc[2][jj]) | (((unsigned)f2bf(acc[3][jj])) << 16);
    u.z = (unsigned)f2bf(acc[4][jj]) | (((unsigned)f2bf(acc[5][jj])) << 16);
    u.w = (unsigned)f2bf(acc[6][jj]) | (((unsigned)f2bf(acc[7][jj])) << 16);
    *reinterpret_cast<uint4*>(v_t + ((long)(b * HH + j)) * KEYS + key0) = u;
  }
}

// ---- shared helper: load split-bf16 Q fragments for one lane's t-row ------
__device__ __forceinline__ void load_qfrags(const unsigned* qp, int g,
                                            bf16x8 qhi[8], bf16x8 qlo[8])
{
  #pragma unroll
  for (int hs = 0; hs < 8; ++hs) {
    const uint4* p = reinterpret_cast<const uint4*>(qp + 16 * hs + 8 * g);
    uint4 a = p[0], c = p[1];
    BF8 hi, lo;
    hi.u[0] = (a.x & 0xffffu) | (a.y << 16);
    hi.u[1] = (a.z & 0xffffu) | (a.w << 16);
    hi.u[2] = (c.x & 0xffffu) | (c.y << 16);
    hi.u[3] = (c.z & 0xffffu) | (c.w << 16);
    lo.u[0] = (a.x >> 16) | (a.y & 0xffff0000u);
    lo.u[1] = (a.z >> 16) | (a.w & 0xffff0000u);
    lo.u[2] = (c.x >> 16) | (c.y & 0xffff0000u);
    lo.u[3] = (c.z >> 16) | (c.w & 0xffff0000u);
    qhi[hs] = hi.v; qlo[hs] = lo.v;
  }
}

// ---------------- pass A: online softmax stats + ssq (MFMA) ----------------
// grid: b(64) x tq(4) x ks(4) = 1024 blocks, 128 thr (2 waves, 32 t each).
__global__ __launch_bounds__(128, 2) void passA_kernel(
    const unsigned* __restrict__ qhl, const unsigned* __restrict__ khl,
    float* __restrict__ m_part, float* __restrict__ l_part,
    float* __restrict__ ssq_part)
{
  __shared__ unsigned short Khi[64 * LDK];
  __shared__ unsigned short Klo[64 * LDK];
  const int tid = threadIdx.x, l = tid & 63, w = tid >> 6;
  const int g = (l >> 5) & 1, lane31 = l & 31;
  const int bx = blockIdx.x, b = bx >> 4, tq = (bx >> 2) & 3, ks = bx & 3;
  const int t0 = tq * 64;

  bf16x8 qhi[8], qlo[8];
  {
    const int t = t0 + 32 * w + lane31;
    load_qfrags(qhl + ((long)(b * TT + t)) * HH, g, qhi, qlo);
  }

  float mreg[16], lreg[16], ssq = 0.f;
  #pragma unroll
  for (int r = 0; r < 16; ++r) { mreg[r] = -1e30f; lreg[r] = 0.f; }

  for (int kt = 0; kt < 16; ++kt) {
    const int kb = ks * 1024 + kt * 64;
    __syncthreads();
    #pragma unroll
    for (int i = 0; i < 16; ++i) {
      int slot = i * 128 + tid;
      int row = slot >> 5, h0 = (slot & 31) << 2;
      uint4 a = *reinterpret_cast<const uint4*>(
          khl + ((long)(b * KEYS + kb + row)) * HH + h0);
      unsigned h01 = (a.x & 0xffffu) | (a.y << 16);
      unsigned h23 = (a.z & 0xffffu) | (a.w << 16);
      unsigned l01 = (a.x >> 16) | (a.y & 0xffff0000u);
      unsigned l23 = (a.z >> 16) | (a.w & 0xffff0000u);
      *reinterpret_cast<uint2*>(&Khi[row * LDK + h0]) = make_uint2(h01, h23);
      *reinterpret_cast<uint2*>(&Klo[row * LDK + h0]) = make_uint2(l01, l23);
    }
    __syncthreads();

    f32x16 acc0 = zero16(), acc1 = zero16();
    #pragma unroll
    for (int hs = 0; hs < 8; ++hs) {
      const int ho = 16 * hs + 8 * g;
      bf16x8 kh0 = *reinterpret_cast<const bf16x8*>(&Khi[lane31 * LDK + ho]);
      bf16x8 kl0 = *reinterpret_cast<const bf16x8*>(&Klo[lane31 * LDK + ho]);
      bf16x8 kh1 = *reinterpret_cast<const bf16x8*>(&Khi[(32 + lane31) * LDK + ho]);
      bf16x8 kl1 = *reinterpret_cast<const bf16x8*>(&Klo[(32 + lane31) * LDK + ho]);
      acc0 = mfma3(qhi[hs], qlo[hs], kh0, kl0, acc0);
      acc1 = mfma3(qhi[hs], qlo[hs], kh1, kl1, acc1);
    }

    const int st0 = (kb + lane31) & 255;
    const int st1 = (kb + 32 + lane31) & 255;
    #pragma unroll
    for (int reg = 0; reg < 16; ++reg) {
      const int tr = t0 + 32 * w + (reg & 3) + 8 * (reg >> 2) + 4 * g;
      float s0 = acc0[reg], s1 = acc1[reg];
      ssq = fmaf(s0, s0, fmaf(s1, s1, ssq));
      bool msk0 = st0 > tr, msk1 = st1 > tr;
      float v0 = msk0 ? -1e30f : s0;
      float v1 = msk1 ? -1e30f : s1;
      float mn = fmaxf(mreg[reg], fmaxf(v0, v1));
      float sc = __expf(mreg[reg] - mn);
      float p0 = msk0 ? 0.f : __expf(s0 - mn);
      float p1 = msk1 ? 0.f : __expf(s1 - mn);
      lreg[reg] = fmaf(lreg[reg], sc, p0 + p1);
      mreg[reg] = mn;
    }
  }

  // butterfly-merge (m,l) across the 32 lanes of each half
  #pragma unroll
  for (int reg = 0; reg < 16; ++reg) {
    #pragma unroll
    for (int off = 1; off < 32; off <<= 1) {
      float mo = __shfl_xor(mreg[reg], off);
      float lo = __shfl_xor(lreg[reg], off);
      float mn = fmaxf(mreg[reg], mo);
      lreg[reg] = lreg[reg] * __expf(mreg[reg] - mn) + lo * __expf(mo - mn);
      mreg[reg] = mn;
    }
  }
  if (lane31 == 0) {
    #pragma unroll
    for (int reg = 0; reg < 16; ++reg) {
      const int tr = t0 + 32 * w + (reg & 3) + 8 * (reg >> 2) + 4 * g;
      m_part[ks * (BB * TT) + b * TT + tr] = mreg[reg];
      l_part[ks * (BB * TT) + b * TT + tr] = lreg[reg];
    }
  }
  // ssq reduce
  #pragma unroll
  for (int off = 1; off < 64; off <<= 1) ssq += __shfl_xor(ssq, off);
  __syncthreads();
  float* red = reinterpret_cast<float*>(Khi);
  if (l == 0) red[w] = ssq;
  __syncthreads();
  if (tid == 0) ssq_part[bx] = red[0] + red[1];
}

// merge key-split partials: m,l
__global__ void merge_ml_kernel(const float* __restrict__ m_part,
                                const float* __restrict__ l_part,
                                float* __restrict__ m_ws,
                                float* __restrict__ l_ws)
{
  int idx = blockIdx.x * 256 + threadIdx.x;
  if (idx >= BB * TT) return;
  float m = -1e30f;
  #pragma unroll
  for (int k = 0; k < 4; ++k) m = fmaxf(m, m_part[k * (BB * TT) + idx]);
  float lsum = 0.f;
  #pragma unroll
  for (int k = 0; k < 4; ++k)
    lsum += l_part[k * (BB * TT) + idx] * __expf(m_part[k * (BB * TT) + idx] - m);
  m_ws[idx] = m;
  l_ws[idx] = lsum;
}

// ---------------- pass B: recompute S, write A, O += A*V (MFMA) ------------
// grid: b(64) x tq(4) x ksb(2) = 512 blocks, 256 thr (4 waves).
// wave quadrants: wt = w&1 (t half), wk = w>>1 (QK key half / PV h half).
__global__ __launch_bounds__(256, 2) void passB_kernel(
    const unsigned* __restrict__ qhl, const unsigned* __restrict__ khl,
    const unsigned short* __restrict__ v_t,
    const float* __restrict__ m_ws, const float* __restrict__ l_ws,
    float* __restrict__ A_out, float* __restrict__ opart)
{
  __shared__ unsigned short Khi[64 * LDK];
  __shared__ unsigned short Klo[64 * LDK];
  __shared__ unsigned short Vt[128 * LDV];
  __shared__ unsigned short As[64 * LDV];
  const int tid = threadIdx.x, l = tid & 63, w = tid >> 6;
  const int g = (l >> 5) & 1, lane31 = l & 31;
  const int wt = w & 1, wk = w >> 1;
  const int bx = blockIdx.x, b = bx >> 3, tq = (bx >> 1) & 3, ksb = bx & 1;
  const int t0 = tq * 64;

  bf16x8 qhi[8], qlo[8];
  {
    const int t = t0 + 32 * wt + lane31;
    load_qfrags(qhl + ((long)(b * TT + t)) * HH, g, qhi, qlo);
  }
  float mreg[16], rinv[16];
  #pragma unroll
  for (int reg = 0; reg < 16; ++reg) {
    const int tr = t0 + 32 * wt + (reg & 3) + 8 * (reg >> 2) + 4 * g;
    mreg[reg] = m_ws[b * TT + tr];
    rinv[reg] = 1.0f / l_ws[b * TT + tr];
  }
  f32x16 o0 = zero16(), o1 = zero16();

  for (int kt = 0; kt < 32; ++kt) {
    const int kb = ksb * 2048 + kt * 64;
    __syncthreads();
    #pragma unroll
    for (int i = 0; i < 8; ++i) {
      int slot = i * 256 + tid;
      int row = slot >> 5, h0 = (slot & 31) << 2;
      uint4 a = *reinterpret_cast<const uint4*>(
          khl + ((long)(b * KEYS + kb + row)) * HH + h0);
      unsigned h01 = (a.x & 0xffffu) | (a.y << 16);
      unsigned h23 = (a.z & 0xffffu) | (a.w << 16);
      unsigned l01 = (a.x >> 16) | (a.y & 0xffff0000u);
      unsigned l23 = (a.z >> 16) | (a.w & 0xffff0000u);
      *reinterpret_cast<uint2*>(&Khi[row * LDK + h0]) = make_uint2(h01, h23);
      *reinterpret_cast<uint2*>(&Klo[row * LDK + h0]) = make_uint2(l01, l23);
    }
    #pragma unroll
    for (int i = 0; i < 4; ++i) {
      int slot = i * 256 + tid;
      int hh = slot >> 3, k0 = (slot & 7) << 3;
      uint4 a = *reinterpret_cast<const uint4*>(
          v_t + ((long)(b * HH + hh)) * KEYS + kb + k0);
      *reinterpret_cast<uint4*>(&Vt[hh * LDV + k0]) = a;
    }
    __syncthreads();

    f32x16 acc = zero16();
    #pragma unroll
    for (int hs = 0; hs < 8; ++hs) {
      const int ho = 16 * hs + 8 * g;
      bf16x8 kh = *reinterpret_cast<const bf16x8*>(
          &Khi[(32 * wk + lane31) * LDK + ho]);
      bf16x8 kl = *reinterpret_cast<const bf16x8*>(
          &Klo[(32 * wk + lane31) * LDK + ho]);
      acc = mfma3(qhi[hs], qlo[hs], kh, kl, acc);
    }

    const int key = kb + 32 * wk + lane31;
    const int st = key & 255;
    #pragma unroll
    for (int reg = 0; reg < 16; ++reg) {
      const int rl = 32 * wt + (reg & 3) + 8 * (reg >> 2) + 4 * g;
      const int tr = t0 + rl;
      float a = (st <= tr) ? __expf(acc[reg] - mreg[reg]) * rinv[reg] : 0.f;
      A_out[((long)(b * TT + tr)) * KEYS + key] = a;
      As[rl * LDV + 32 * wk + lane31] = f2bf(a);
    }
    __syncthreads();

    #pragma unroll
    for (int ksx = 0; ksx < 4; ++ksx) {
      const int ko = 16 * ksx + 8 * g;
      bf16x8 af = *reinterpret_cast<const bf16x8*>(
          &As[(32 * wt + lane31) * LDV + ko]);
      bf16x8 v0 = *reinterpret_cast<const bf16x8*>(
          &Vt[(64 * wk + lane31) * LDV + ko]);
      bf16x8 v1 = *reinterpret_cast<const bf16x8*>(
          &Vt[(64 * wk + 32 + lane31) * LDV + ko]);
      o0 = __builtin_amdgcn_mfma_f32_32x32x16_bf16(af, v0, o0, 0, 0, 0);
      o1 = __builtin_amdgcn_mfma_f32_32x32x16_bf16(af, v1, o1, 0, 0, 0);
    }
  }

  #pragma unroll
  for (int reg = 0; reg < 16; ++reg) {
    const int tr = t0 + 32 * wt + (reg & 3) + 8 * (reg >> 2) + 4 * g;
    long base = (long)ksb * (BB * TT * HH) + ((long)(b * TT + tr)) * HH + 64 * wk;
    opart[base + lane31]      = o0[reg];
    opart[base + 32 + lane31] = o1[reg];
  }
}

__global__ void reduce_out_kernel(const float* __restrict__ opart,
                                  float* __restrict__ out)
{
  int i = blockIdx.x * 256 + threadIdx.x;          // float4 index
  const int n4 = BB * TT * HH / 4;
  if (i >= n4) return;
  const float4* p0 = reinterpret_cast<const float4*>(opart);
  const float4* p1 = reinterpret_cast<const float4*>(opart + BB * TT * HH);
  float4 a = p0[i], c = p1[i];
  a.x += c.x; a.y += c.y; a.z += c.z; a.w += c.w;
  *reinterpret_cast<float4*>(out + 4 * (long)i) = a;
}

__global__ void finalize_kernel(const float* __restrict__ ssq_part,
                                float* __restrict__ S_norm)
{
  int b = threadIdx.x;
  if (b < BB) {
    float s = 0.f;
    #pragma unroll
    for (int i = 0; i < 16; ++i) s += ssq_part[b * 16 + i];
    S_norm[b] = sqrtf(s);
  }
}

extern "C" void kernel_launch(void* const* d_in, const int* in_sizes, int n_in,
                              void* d_out, int out_size, void* d_ws, size_t ws_size,
                              hipStream_t stream)
{
  const float* node  = (const float*)d_in[0];
  const float* neigh = (const float*)d_in[1];
  const float* Wq = (const float*)d_in[4];
  const float* bq = (const float*)d_in[5];
  const float* Wk = (const float*)d_in[6];
  const float* bk = (const float*)d_in[7];
  const float* Wv = (const float*)d_in[8];
  const float* bv = (const float*)d_in[9];

  float* out    = (float*)d_out;
  float* A_out  = out + (long)BB * TT * HH;
  float* S_norm = A_out + (long)BB * TT * KEYS;

  unsigned* qhl = (unsigned*)d_ws;                       // B*T*H u32
  unsigned* khl = qhl + (long)BB * TT * HH;              // B*KEYS*H u32
  unsigned short* v_t = (unsigned short*)(khl + (long)BB * KEYS * HH); // B*H*KEYS bf16
  float* m_part = (float*)(v_t + (long)BB * HH * KEYS);  // 4*B*T
  float* l_part = m_part + 4 * BB * TT;
  float* ssq_part = l_part + 4 * BB * TT;                // 1024
  float* opart = ssq_part + 1024;                        // 2*B*T*H
  float* m_ws  = opart + 2L * BB * TT * HH;              // B*T
  float* l_ws  = m_ws + BB * TT;

  hipLaunchKernelGGL(proj_pack_kernel, dim3(BB * TT / 128), dim3(256), 0, stream,
                     node, neigh, Wq, bq, qhl, 0);
  hipLaunchKernelGGL(proj_pack_kernel, dim3(BB * KEYS / 128), dim3(256), 0, stream,
                     node, neigh, Wk, bk, khl, 1);
  hipLaunchKernelGGL(proj_vt_kernel, dim3(BB * KEYS / 128), dim3(256), 0, stream,
                     node, neigh, Wv, bv, v_t);
  hipLaunchKernelGGL(passA_kernel, dim3(BB * 16), dim3(128), 0, stream,
                     qhl, khl, m_part, l_part, ssq_part);
  hipLaunchKernelGGL(merge_ml_kernel, dim3((BB * TT + 255) / 256), dim3(256), 0, stream,
                     m_part, l_part, m_ws, l_ws);
  hipLaunchKernelGGL(passB_kernel, dim3(BB * 8), dim3(256), 0, stream,
                     qhl, khl, v_t, m_ws, l_ws, A_out, opart);
  hipLaunchKernelGGL(reduce_out_kernel, dim3((BB * TT * HH / 4 + 255) / 256), dim3(256),
                     0, stream, opart, out);
  hipLaunchKernelGGL(finalize_kernel, dim3(1), dim3(64), 0, stream,
                     ssq_part, S_norm);
}

// Round 3
// 406.072 us; speedup vs baseline: 3.4782x; 1.6584x over previous
//
#include <hip/hip_runtime.h>
#include <math.h>

// JointAttention B=64, N+1=16, T=256, H=128, TEMP=1
// R3: split-bf16 MFMA projections, fused K+V (V emitted transposed).
// Attention passes unchanged from R2 (MFMA, split-bf16 QK^T, bf16 AV).

constexpr int BB   = 64;
constexpr int TT   = 256;
constexpr int HH   = 128;
constexpr int KEYS = 4096;
constexpr int LDK  = 136;   // bf16 K-tile pad
constexpr int LDV  = 72;    // bf16 Vt/As pad
constexpr int LDX  = 130;   // packed-u32 x-tile pad (proj)

typedef __attribute__((ext_vector_type(8)))  __bf16 bf16x8;
typedef __attribute__((ext_vector_type(16))) float  f32x16;

union BF8 { unsigned u[4]; bf16x8 v; };

__device__ __forceinline__ float4 ld4(const float* p) {
  return *reinterpret_cast<const float4*>(p);
}
__device__ __forceinline__ unsigned short f2bf(float x) {
  unsigned u = __float_as_uint(x);
  return (unsigned short)((u + 0x7fffu + ((u >> 16) & 1u)) >> 16);
}
__device__ __forceinline__ float bf2f(unsigned short h) {
  return __uint_as_float(((unsigned)h) << 16);
}
__device__ __forceinline__ unsigned packhl(float x) {
  unsigned short hi = f2bf(x);
  unsigned short lo = f2bf(x - bf2f(hi));
  return (unsigned)hi | (((unsigned)lo) << 16);
}
__device__ __forceinline__ void split2(float f0, float f1,
                                       unsigned& hw, unsigned& lw) {
  unsigned short h0 = f2bf(f0), h1 = f2bf(f1);
  unsigned short l0 = f2bf(f0 - bf2f(h0)), l1 = f2bf(f1 - bf2f(h1));
  hw = (unsigned)h0 | (((unsigned)h1) << 16);
  lw = (unsigned)l0 | (((unsigned)l1) << 16);
}
// 8 packed u32 (hi|lo<<16 per element) -> hi/lo bf16x8 fragments
__device__ __forceinline__ void unpack8(const unsigned* p,
                                        bf16x8& hi, bf16x8& lo) {
  uint4 a = *reinterpret_cast<const uint4*>(p);
  uint4 c = *reinterpret_cast<const uint4*>(p + 4);
  BF8 H, L;
  H.u[0] = (a.x & 0xffffu) | (a.y << 16);
  H.u[1] = (a.z & 0xffffu) | (a.w << 16);
  H.u[2] = (c.x & 0xffffu) | (c.y << 16);
  H.u[3] = (c.z & 0xffffu) | (c.w << 16);
  L.u[0] = (a.x >> 16) | (a.y & 0xffff0000u);
  L.u[1] = (a.z >> 16) | (a.w & 0xffff0000u);
  L.u[2] = (c.x >> 16) | (c.y & 0xffff0000u);
  L.u[3] = (c.z >> 16) | (c.w & 0xffff0000u);
  hi = H.v; lo = L.v;
}
__device__ __forceinline__ f32x16 zero16() {
  f32x16 z;
  #pragma unroll
  for (int i = 0; i < 16; ++i) z[i] = 0.f;
  return z;
}
__device__ __forceinline__ f32x16 mfma3(bf16x8 ahi, bf16x8 alo,
                                        bf16x8 bhi, bf16x8 blo, f32x16 c) {
  c = __builtin_amdgcn_mfma_f32_32x32x16_bf16(ahi, bhi, c, 0, 0, 0);
  c = __builtin_amdgcn_mfma_f32_32x32x16_bf16(ahi, blo, c, 0, 0, 0);
  c = __builtin_amdgcn_mfma_f32_32x32x16_bf16(alo, bhi, c, 0, 0, 0);
  return c;
}

// ------------- MFMA projection: y = x @ W^T + b (split-bf16) --------------
// 128 rows/block, 256 thr (4 waves). Wave w owns j in [32w, 32w+32).
// K path: C[key][j] = mfma3(A=x, B=Wk). DOV also: Vt C[j][key] = mfma3(A=Wv, B=x).
// mode 0: rows from node (q). mode 1: rows from kv = [node, neigh].
template<bool DOV>
__global__ __launch_bounds__(256, 2) void proj_mfma_kernel(
    const float* __restrict__ node, const float* __restrict__ neigh,
    const float* __restrict__ Wk_, const float* __restrict__ bk_,
    const float* __restrict__ Wv_, const float* __restrict__ bv_,
    unsigned* __restrict__ khl, unsigned short* __restrict__ v_t, int mode)
{
  __shared__ unsigned xp[128 * LDX];
  const int tid = threadIdx.x;
  const long r0 = (long)blockIdx.x * 128;

  #pragma unroll
  for (int i = 0; i < 16; ++i) {
    int slot = tid + 256 * i;
    int row = slot >> 5, h0 = (slot & 31) << 2;
    long r = r0 + row;
    const float* src;
    if (mode == 0) {
      src = node + r * HH;
    } else {
      long bb = r >> 12;
      int  n  = (int)((r >> 8) & 15);
      int  t  = (int)(r & 255);
      src = (n == 0) ? (node + (bb * TT + t) * HH)
                     : (neigh + ((bb * 15 + (n - 1)) * (long)TT + t) * HH);
    }
    float4 xv = ld4(src + h0);
    uint4 u;
    u.x = packhl(xv.x); u.y = packhl(xv.y);
    u.z = packhl(xv.z); u.w = packhl(xv.w);
    *reinterpret_cast<uint4*>(&xp[row * LDX + h0]) = u;
  }
  __syncthreads();

  const int l = tid & 63, w = tid >> 6, g = l >> 5, lane31 = l & 31;
  const int j = 32 * w + lane31;   // this lane's W row (B-frag col for K, A-frag row for V)

  f32x16 accK[4];
  #pragma unroll
  for (int kt = 0; kt < 4; ++kt) accK[kt] = zero16();
  f32x16 accV[4];
  if constexpr (DOV) {
    #pragma unroll
    for (int kt = 0; kt < 4; ++kt) accV[kt] = zero16();
  }

  #pragma unroll
  for (int hs = 0; hs < 8; ++hs) {
    const int ho = 16 * hs + 8 * g;
    // W_k fragment for this hs
    float4 wa = ld4(Wk_ + j * HH + ho), wb = ld4(Wk_ + j * HH + ho + 4);
    BF8 WH, WL;
    split2(wa.x, wa.y, WH.u[0], WL.u[0]);
    split2(wa.z, wa.w, WH.u[1], WL.u[1]);
    split2(wb.x, wb.y, WH.u[2], WL.u[2]);
    split2(wb.z, wb.w, WH.u[3], WL.u[3]);
    // x fragments, 4 row-tiles
    bf16x8 xhi[4], xlo[4];
    #pragma unroll
    for (int rt = 0; rt < 4; ++rt)
      unpack8(&xp[(32 * rt + lane31) * LDX + ho], xhi[rt], xlo[rt]);
    #pragma unroll
    for (int rt = 0; rt < 4; ++rt)
      accK[rt] = mfma3(xhi[rt], xlo[rt], WH.v, WL.v, accK[rt]);
    if constexpr (DOV) {
      float4 va = ld4(Wv_ + j * HH + ho), vb = ld4(Wv_ + j * HH + ho + 4);
      BF8 VH, VL;
      split2(va.x, va.y, VH.u[0], VL.u[0]);
      split2(va.z, va.w, VH.u[1], VL.u[1]);
      split2(vb.x, vb.y, VH.u[2], VL.u[2]);
      split2(vb.z, vb.w, VH.u[3], VL.u[3]);
      #pragma unroll
      for (int rt = 0; rt < 4; ++rt)
        accV[rt] = mfma3(VH.v, VL.v, xhi[rt], xlo[rt], accV[rt]);
    }
  }

  // K epilogue: add bias, pack hi|lo, store [row][j]
  const float bK = bk_[j];
  #pragma unroll
  for (int kt = 0; kt < 4; ++kt) {
    #pragma unroll
    for (int reg = 0; reg < 16; ++reg) {
      int rm = (reg & 3) + 8 * (reg >> 2) + 4 * g;
      long r = r0 + 32 * kt + rm;
      khl[r * HH + j] = packhl(accK[kt][reg] + bK);
    }
  }
  if constexpr (DOV) {
    const int bidx = (int)(r0 >> 12);
    const int key0 = (int)(r0 & (KEYS - 1));
    float bvr[16];
    #pragma unroll
    for (int reg = 0; reg < 16; ++reg)
      bvr[reg] = bv_[32 * w + (reg & 3) + 8 * (reg >> 2) + 4 * g];
    #pragma unroll
    for (int kt = 0; kt < 4; ++kt) {
      #pragma unroll
      for (int reg = 0; reg < 16; ++reg) {
        int rm = (reg & 3) + 8 * (reg >> 2) + 4 * g;
        int jrow = 32 * w + rm;
        v_t[((long)(bidx * HH + jrow)) * KEYS + key0 + 32 * kt + lane31] =
            f2bf(accV[kt][reg] + bvr[reg]);
      }
    }
  }
}

// ---- shared helper: load split-bf16 Q fragments for one lane's t-row ------
__device__ __forceinline__ void load_qfrags(const unsigned* qp, int g,
                                            bf16x8 qhi[8], bf16x8 qlo[8])
{
  #pragma unroll
  for (int hs = 0; hs < 8; ++hs)
    unpack8(qp + 16 * hs + 8 * g, qhi[hs], qlo[hs]);
}

// ---------------- pass A: online softmax stats + ssq (MFMA) ----------------
__global__ __launch_bounds__(128, 2) void passA_kernel(
    const unsigned* __restrict__ qhl, const unsigned* __restrict__ khl,
    float* __restrict__ m_part, float* __restrict__ l_part,
    float* __restrict__ ssq_part)
{
  __shared__ unsigned short Khi[64 * LDK];
  __shared__ unsigned short Klo[64 * LDK];
  const int tid = threadIdx.x, l = tid & 63, w = tid >> 6;
  const int g = (l >> 5) & 1, lane31 = l & 31;
  const int bx = blockIdx.x, b = bx >> 4, tq = (bx >> 2) & 3, ks = bx & 3;
  const int t0 = tq * 64;

  bf16x8 qhi[8], qlo[8];
  {
    const int t = t0 + 32 * w + lane31;
    load_qfrags(qhl + ((long)(b * TT + t)) * HH, g, qhi, qlo);
  }

  float mreg[16], lreg[16], ssq = 0.f;
  #pragma unroll
  for (int r = 0; r < 16; ++r) { mreg[r] = -1e30f; lreg[r] = 0.f; }

  for (int kt = 0; kt < 16; ++kt) {
    const int kb = ks * 1024 + kt * 64;
    __syncthreads();
    #pragma unroll
    for (int i = 0; i < 16; ++i) {
      int slot = i * 128 + tid;
      int row = slot >> 5, h0 = (slot & 31) << 2;
      uint4 a = *reinterpret_cast<const uint4*>(
          khl + ((long)(b * KEYS + kb + row)) * HH + h0);
      unsigned h01 = (a.x & 0xffffu) | (a.y << 16);
      unsigned h23 = (a.z & 0xffffu) | (a.w << 16);
      unsigned l01 = (a.x >> 16) | (a.y & 0xffff0000u);
      unsigned l23 = (a.z >> 16) | (a.w & 0xffff0000u);
      *reinterpret_cast<uint2*>(&Khi[row * LDK + h0]) = make_uint2(h01, h23);
      *reinterpret_cast<uint2*>(&Klo[row * LDK + h0]) = make_uint2(l01, l23);
    }
    __syncthreads();

    f32x16 acc0 = zero16(), acc1 = zero16();
    #pragma unroll
    for (int hs = 0; hs < 8; ++hs) {
      const int ho = 16 * hs + 8 * g;
      bf16x8 kh0 = *reinterpret_cast<const bf16x8*>(&Khi[lane31 * LDK + ho]);
      bf16x8 kl0 = *reinterpret_cast<const bf16x8*>(&Klo[lane31 * LDK + ho]);
      bf16x8 kh1 = *reinterpret_cast<const bf16x8*>(&Khi[(32 + lane31) * LDK + ho]);
      bf16x8 kl1 = *reinterpret_cast<const bf16x8*>(&Klo[(32 + lane31) * LDK + ho]);
      acc0 = mfma3(qhi[hs], qlo[hs], kh0, kl0, acc0);
      acc1 = mfma3(qhi[hs], qlo[hs], kh1, kl1, acc1);
    }

    const int st0 = (kb + lane31) & 255;
    const int st1 = (kb + 32 + lane31) & 255;
    #pragma unroll
    for (int reg = 0; reg < 16; ++reg) {
      const int tr = t0 + 32 * w + (reg & 3) + 8 * (reg >> 2) + 4 * g;
      float s0 = acc0[reg], s1 = acc1[reg];
      ssq = fmaf(s0, s0, fmaf(s1, s1, ssq));
      bool msk0 = st0 > tr, msk1 = st1 > tr;
      float v0 = msk0 ? -1e30f : s0;
      float v1 = msk1 ? -1e30f : s1;
      float mn = fmaxf(mreg[reg], fmaxf(v0, v1));
      float sc = __expf(mreg[reg] - mn);
      float p0 = msk0 ? 0.f : __expf(s0 - mn);
      float p1 = msk1 ? 0.f : __expf(s1 - mn);
      lreg[reg] = fmaf(lreg[reg], sc, p0 + p1);
      mreg[reg] = mn;
    }
  }

  #pragma unroll
  for (int reg = 0; reg < 16; ++reg) {
    #pragma unroll
    for (int off = 1; off < 32; off <<= 1) {
      float mo = __shfl_xor(mreg[reg], off);
      float lo = __shfl_xor(lreg[reg], off);
      float mn = fmaxf(mreg[reg], mo);
      lreg[reg] = lreg[reg] * __expf(mreg[reg] - mn) + lo * __expf(mo - mn);
      mreg[reg] = mn;
    }
  }
  if (lane31 == 0) {
    #pragma unroll
    for (int reg = 0; reg < 16; ++reg) {
      const int tr = t0 + 32 * w + (reg & 3) + 8 * (reg >> 2) + 4 * g;
      m_part[ks * (BB * TT) + b * TT + tr] = mreg[reg];
      l_part[ks * (BB * TT) + b * TT + tr] = lreg[reg];
    }
  }
  #pragma unroll
  for (int off = 1; off < 64; off <<= 1) ssq += __shfl_xor(ssq, off);
  __syncthreads();
  float* red = reinterpret_cast<float*>(Khi);
  if (l == 0) red[w] = ssq;
  __syncthreads();
  if (tid == 0) ssq_part[bx] = red[0] + red[1];
}

__global__ void merge_ml_kernel(const float* __restrict__ m_part,
                                const float* __restrict__ l_part,
                                float* __restrict__ m_ws,
                                float* __restrict__ l_ws)
{
  int idx = blockIdx.x * 256 + threadIdx.x;
  if (idx >= BB * TT) return;
  float m = -1e30f;
  #pragma unroll
  for (int k = 0; k < 4; ++k) m = fmaxf(m, m_part[k * (BB * TT) + idx]);
  float lsum = 0.f;
  #pragma unroll
  for (int k = 0; k < 4; ++k)
    lsum += l_part[k * (BB * TT) + idx] * __expf(m_part[k * (BB * TT) + idx] - m);
  m_ws[idx] = m;
  l_ws[idx] = lsum;
}

// ---------------- pass B: recompute S, write A, O += A*V (MFMA) ------------
__global__ __launch_bounds__(256, 2) void passB_kernel(
    const unsigned* __restrict__ qhl, const unsigned* __restrict__ khl,
    const unsigned short* __restrict__ v_t,
    const float* __restrict__ m_ws, const float* __restrict__ l_ws,
    float* __restrict__ A_out, float* __restrict__ opart)
{
  __shared__ unsigned short Khi[64 * LDK];
  __shared__ unsigned short Klo[64 * LDK];
  __shared__ unsigned short Vt[128 * LDV];
  __shared__ unsigned short As[64 * LDV];
  const int tid = threadIdx.x, l = tid & 63, w = tid >> 6;
  const int g = (l >> 5) & 1, lane31 = l & 31;
  const int wt = w & 1, wk = w >> 1;
  const int bx = blockIdx.x, b = bx >> 3, tq = (bx >> 1) & 3, ksb = bx & 1;
  const int t0 = tq * 64;

  bf16x8 qhi[8], qlo[8];
  {
    const int t = t0 + 32 * wt + lane31;
    load_qfrags(qhl + ((long)(b * TT + t)) * HH, g, qhi, qlo);
  }
  float mreg[16], rinv[16];
  #pragma unroll
  for (int reg = 0; reg < 16; ++reg) {
    const int tr = t0 + 32 * wt + (reg & 3) + 8 * (reg >> 2) + 4 * g;
    mreg[reg] = m_ws[b * TT + tr];
    rinv[reg] = 1.0f / l_ws[b * TT + tr];
  }
  f32x16 o0 = zero16(), o1 = zero16();

  for (int kt = 0; kt < 32; ++kt) {
    const int kb = ksb * 2048 + kt * 64;
    __syncthreads();
    #pragma unroll
    for (int i = 0; i < 8; ++i) {
      int slot = i * 256 + tid;
      int row = slot >> 5, h0 = (slot & 31) << 2;
      uint4 a = *reinterpret_cast<const uint4*>(
          khl + ((long)(b * KEYS + kb + row)) * HH + h0);
      unsigned h01 = (a.x & 0xffffu) | (a.y << 16);
      unsigned h23 = (a.z & 0xffffu) | (a.w << 16);
      unsigned l01 = (a.x >> 16) | (a.y & 0xffff0000u);
      unsigned l23 = (a.z >> 16) | (a.w & 0xffff0000u);
      *reinterpret_cast<uint2*>(&Khi[row * LDK + h0]) = make_uint2(h01, h23);
      *reinterpret_cast<uint2*>(&Klo[row * LDK + h0]) = make_uint2(l01, l23);
    }
    #pragma unroll
    for (int i = 0; i < 4; ++i) {
      int slot = i * 256 + tid;
      int hh = slot >> 3, k0 = (slot & 7) << 3;
      uint4 a = *reinterpret_cast<const uint4*>(
          v_t + ((long)(b * HH + hh)) * KEYS + kb + k0);
      *reinterpret_cast<uint4*>(&Vt[hh * LDV + k0]) = a;
    }
    __syncthreads();

    f32x16 acc = zero16();
    #pragma unroll
    for (int hs = 0; hs < 8; ++hs) {
      const int ho = 16 * hs + 8 * g;
      bf16x8 kh = *reinterpret_cast<const bf16x8*>(
          &Khi[(32 * wk + lane31) * LDK + ho]);
      bf16x8 kl = *reinterpret_cast<const bf16x8*>(
          &Klo[(32 * wk + lane31) * LDK + ho]);
      acc = mfma3(qhi[hs], qlo[hs], kh, kl, acc);
    }

    const int key = kb + 32 * wk + lane31;
    const int st = key & 255;
    #pragma unroll
    for (int reg = 0; reg < 16; ++reg) {
      const int rl = 32 * wt + (reg & 3) + 8 * (reg >> 2) + 4 * g;
      const int tr = t0 + rl;
      float a = (st <= tr) ? __expf(acc[reg] - mreg[reg]) * rinv[reg] : 0.f;
      A_out[((long)(b * TT + tr)) * KEYS + key] = a;
      As[rl * LDV + 32 * wk + lane31] = f2bf(a);
    }
    __syncthreads();

    #pragma unroll
    for (int ksx = 0; ksx < 4; ++ksx) {
      const int ko = 16 * ksx + 8 * g;
      bf16x8 af = *reinterpret_cast<const bf16x8*>(
          &As[(32 * wt + lane31) * LDV + ko]);
      bf16x8 v0 = *reinterpret_cast<const bf16x8*>(
          &Vt[(64 * wk + lane31) * LDV + ko]);
      bf16x8 v1 = *reinterpret_cast<const bf16x8*>(
          &Vt[(64 * wk + 32 + lane31) * LDV + ko]);
      o0 = __builtin_amdgcn_mfma_f32_32x32x16_bf16(af, v0, o0, 0, 0, 0);
      o1 = __builtin_amdgcn_mfma_f32_32x32x16_bf16(af, v1, o1, 0, 0, 0);
    }
  }

  #pragma unroll
  for (int reg = 0; reg < 16; ++reg) {
    const int tr = t0 + 32 * wt + (reg & 3) + 8 * (reg >> 2) + 4 * g;
    long base = (long)ksb * (BB * TT * HH) + ((long)(b * TT + tr)) * HH + 64 * wk;
    opart[base + lane31]      = o0[reg];
    opart[base + 32 + lane31] = o1[reg];
  }
}

__global__ void reduce_out_kernel(const float* __restrict__ opart,
                                  float* __restrict__ out)
{
  int i = blockIdx.x * 256 + threadIdx.x;
  const int n4 = BB * TT * HH / 4;
  if (i >= n4) return;
  const float4* p0 = reinterpret_cast<const float4*>(opart);
  const float4* p1 = reinterpret_cast<const float4*>(opart + BB * TT * HH);
  float4 a = p0[i], c = p1[i];
  a.x += c.x; a.y += c.y; a.z += c.z; a.w += c.w;
  *reinterpret_cast<float4*>(out + 4 * (long)i) = a;
}

__global__ void finalize_kernel(const float* __restrict__ ssq_part,
                                float* __restrict__ S_norm)
{
  int b = threadIdx.x;
  if (b < BB) {
    float s = 0.f;
    #pragma unroll
    for (int i = 0; i < 16; ++i) s += ssq_part[b * 16 + i];
    S_norm[b] = sqrtf(s);
  }
}

extern "C" void kernel_launch(void* const* d_in, const int* in_sizes, int n_in,
                              void* d_out, int out_size, void* d_ws, size_t ws_size,
                              hipStream_t stream)
{
  const float* node  = (const float*)d_in[0];
  const float* neigh = (const float*)d_in[1];
  const float* Wq = (const float*)d_in[4];
  const float* bq = (const float*)d_in[5];
  const float* Wk = (const float*)d_in[6];
  const float* bk = (const float*)d_in[7];
  const float* Wv = (const float*)d_in[8];
  const float* bv = (const float*)d_in[9];

  float* out    = (float*)d_out;
  float* A_out  = out + (long)BB * TT * HH;
  float* S_norm = A_out + (long)BB * TT * KEYS;

  unsigned* qhl = (unsigned*)d_ws;                       // B*T*H u32
  unsigned* khl = qhl + (long)BB * TT * HH;              // B*KEYS*H u32
  unsigned short* v_t = (unsigned short*)(khl + (long)BB * KEYS * HH); // B*H*KEYS bf16
  float* m_part = (float*)(v_t + (long)BB * HH * KEYS);  // 4*B*T
  float* l_part = m_part + 4 * BB * TT;
  float* ssq_part = l_part + 4 * BB * TT;                // 1024
  float* opart = ssq_part + 1024;                        // 2*B*T*H
  float* m_ws  = opart + 2L * BB * TT * HH;              // B*T
  float* l_ws  = m_ws + BB * TT;

  proj_mfma_kernel<false><<<dim3(BB * TT / 128), dim3(256), 0, stream>>>(
      node, neigh, Wq, bq, Wq, bq, qhl, v_t, 0);
  proj_mfma_kernel<true><<<dim3(BB * KEYS / 128), dim3(256), 0, stream>>>(
      node, neigh, Wk, bk, Wv, bv, khl, v_t, 1);
  passA_kernel<<<dim3(BB * 16), dim3(128), 0, stream>>>(
      qhl, khl, m_part, l_part, ssq_part);
  merge_ml_kernel<<<dim3((BB * TT + 255) / 256), dim3(256), 0, stream>>>(
      m_part, l_part, m_ws, l_ws);
  passB_kernel<<<dim3(BB * 8), dim3(256), 0, stream>>>(
      qhl, khl, v_t, m_ws, l_ws, A_out, opart);
  reduce_out_kernel<<<dim3((BB * TT * HH / 4 + 255) / 256), dim3(256), 0, stream>>>(
      opart, out);
  finalize_kernel<<<dim3(1), dim3(64), 0, stream>>>(ssq_part, S_norm);
}

// Round 4
// 385.005 us; speedup vs baseline: 3.6686x; 1.0547x over previous
//
#include <hip/hip_runtime.h>
#include <math.h>

// JointAttention B=64, N+1=16, T=256, H=128, TEMP=1
// R4: hi/lo bf16 PLANES everywhere (no packed-u32), native bf16 cvt,
// pre-split weights, XCD-aware swizzle for passA/passB.

constexpr int BB   = 64;
constexpr int TT   = 256;
constexpr int HH   = 128;
constexpr int KEYS = 4096;
constexpr int LDK  = 136;   // bf16 row pad (272B)
constexpr int LDV  = 72;    // bf16 Vt/As pad

typedef __attribute__((ext_vector_type(8)))  __bf16 bf16x8;
typedef __attribute__((ext_vector_type(16))) float  f32x16;
typedef unsigned short ushort_t;

__device__ __forceinline__ float4 ld4(const float* p) {
  return *reinterpret_cast<const float4*>(p);
}
__device__ __forceinline__ ushort_t f2bf(float x) {
  union { __bf16 b; ushort_t u; } c; c.b = (__bf16)x; return c.u;
}
__device__ __forceinline__ float bf2f(ushort_t h) {
  return __uint_as_float(((unsigned)h) << 16);
}
__device__ __forceinline__ void splitf(float x, ushort_t& h, ushort_t& l) {
  h = f2bf(x);
  l = f2bf(x - bf2f(h));
}
__device__ __forceinline__ f32x16 zero16() {
  f32x16 z;
  #pragma unroll
  for (int i = 0; i < 16; ++i) z[i] = 0.f;
  return z;
}
__device__ __forceinline__ f32x16 mfma3(bf16x8 ahi, bf16x8 alo,
                                        bf16x8 bhi, bf16x8 blo, f32x16 c) {
  c = __builtin_amdgcn_mfma_f32_32x32x16_bf16(ahi, bhi, c, 0, 0, 0);
  c = __builtin_amdgcn_mfma_f32_32x32x16_bf16(ahi, blo, c, 0, 0, 0);
  c = __builtin_amdgcn_mfma_f32_32x32x16_bf16(alo, bhi, c, 0, 0, 0);
  return c;
}

// ------------- pre-split weights into hi/lo bf16 planes --------------------
__global__ __launch_bounds__(256) void prep_w_kernel(
    const float* __restrict__ Wq, const float* __restrict__ Wk,
    const float* __restrict__ Wv,
    ushort_t* __restrict__ wqh, ushort_t* __restrict__ wql,
    ushort_t* __restrict__ wkh, ushort_t* __restrict__ wkl,
    ushort_t* __restrict__ wvh, ushort_t* __restrict__ wvl)
{
  int i = blockIdx.x * 256 + threadIdx.x;
  if (i >= HH * HH) return;
  ushort_t h, l;
  splitf(Wq[i], h, l); wqh[i] = h; wql[i] = l;
  splitf(Wk[i], h, l); wkh[i] = h; wkl[i] = l;
  splitf(Wv[i], h, l); wvh[i] = h; wvl[i] = l;
}

// ------------- MFMA projection: y = x @ W^T + b (split-bf16) --------------
// 128 rows/block, 256 thr (4 waves). Wave w owns j in [32w, 32w+32).
// K path: C[row][j] = x @ Wk^T. DOV: Vt C[j][key] = Wv @ x^T (pre-transposed).
template<bool DOV>
__global__ __launch_bounds__(256, 2) void proj_kernel(
    const float* __restrict__ node, const float* __restrict__ neigh,
    const ushort_t* __restrict__ W1h, const ushort_t* __restrict__ W1l,
    const float* __restrict__ b1,
    const ushort_t* __restrict__ WVh, const ushort_t* __restrict__ WVl,
    const float* __restrict__ bV,
    ushort_t* __restrict__ yh, ushort_t* __restrict__ yl,
    ushort_t* __restrict__ v_t, int mode)
{
  __shared__ ushort_t xh[128 * LDK];
  __shared__ ushort_t xl[128 * LDK];
  const int tid = threadIdx.x;
  const long r0 = (long)blockIdx.x * 128;

  #pragma unroll
  for (int i = 0; i < 16; ++i) {
    int slot = tid + 256 * i;
    int row = slot >> 5, h0 = (slot & 31) << 2;
    long r = r0 + row;
    const float* src;
    if (mode == 0) {
      src = node + r * HH;
    } else {
      long bb = r >> 12;
      int  n  = (int)((r >> 8) & 15);
      int  t  = (int)(r & 255);
      src = (n == 0) ? (node + (bb * TT + t) * HH)
                     : (neigh + ((bb * 15 + (n - 1)) * (long)TT + t) * HH);
    }
    float4 xv = ld4(src + h0);
    ushort_t h0h, h0l, h1h, h1l, h2h, h2l, h3h, h3l;
    splitf(xv.x, h0h, h0l); splitf(xv.y, h1h, h1l);
    splitf(xv.z, h2h, h2l); splitf(xv.w, h3h, h3l);
    *reinterpret_cast<uint2*>(&xh[row * LDK + h0]) =
        make_uint2((unsigned)h0h | ((unsigned)h1h << 16),
                   (unsigned)h2h | ((unsigned)h3h << 16));
    *reinterpret_cast<uint2*>(&xl[row * LDK + h0]) =
        make_uint2((unsigned)h0l | ((unsigned)h1l << 16),
                   (unsigned)h2l | ((unsigned)h3l << 16));
  }
  __syncthreads();

  const int l = tid & 63, w = tid >> 6, g = l >> 5, lane31 = l & 31;
  const int j = 32 * w + lane31;

  f32x16 accK[4];
  #pragma unroll
  for (int kt = 0; kt < 4; ++kt) accK[kt] = zero16();
  f32x16 accV[4];
  if constexpr (DOV) {
    #pragma unroll
    for (int kt = 0; kt < 4; ++kt) accV[kt] = zero16();
  }

  #pragma unroll
  for (int hs = 0; hs < 8; ++hs) {
    const int ho = 16 * hs + 8 * g;
    bf16x8 wh = *reinterpret_cast<const bf16x8*>(W1h + j * HH + ho);
    bf16x8 wl = *reinterpret_cast<const bf16x8*>(W1l + j * HH + ho);
    bf16x8 xhf[4], xlf[4];
    #pragma unroll
    for (int rt = 0; rt < 4; ++rt) {
      xhf[rt] = *reinterpret_cast<const bf16x8*>(&xh[(32 * rt + lane31) * LDK + ho]);
      xlf[rt] = *reinterpret_cast<const bf16x8*>(&xl[(32 * rt + lane31) * LDK + ho]);
    }
    #pragma unroll
    for (int rt = 0; rt < 4; ++rt)
      accK[rt] = mfma3(xhf[rt], xlf[rt], wh, wl, accK[rt]);
    if constexpr (DOV) {
      bf16x8 vh = *reinterpret_cast<const bf16x8*>(WVh + j * HH + ho);
      bf16x8 vl = *reinterpret_cast<const bf16x8*>(WVl + j * HH + ho);
      #pragma unroll
      for (int rt = 0; rt < 4; ++rt)
        accV[rt] = mfma3(vh, vl, xhf[rt], xlf[rt], accV[rt]);
    }
  }

  const float bK = b1[j];
  #pragma unroll
  for (int kt = 0; kt < 4; ++kt) {
    #pragma unroll
    for (int reg = 0; reg < 16; ++reg) {
      int rm = (reg & 3) + 8 * (reg >> 2) + 4 * g;
      long r = r0 + 32 * kt + rm;
      ushort_t h, lo_;
      splitf(accK[kt][reg] + bK, h, lo_);
      yh[r * HH + j] = h;
      yl[r * HH + j] = lo_;
    }
  }
  if constexpr (DOV) {
    const int bidx = (int)(r0 >> 12);
    const int key0 = (int)(r0 & (KEYS - 1));
    float bvr[16];
    #pragma unroll
    for (int reg = 0; reg < 16; ++reg)
      bvr[reg] = bV[32 * w + (reg & 3) + 8 * (reg >> 2) + 4 * g];
    #pragma unroll
    for (int kt = 0; kt < 4; ++kt) {
      #pragma unroll
      for (int reg = 0; reg < 16; ++reg) {
        int rm = (reg & 3) + 8 * (reg >> 2) + 4 * g;
        int jrow = 32 * w + rm;
        v_t[((long)(bidx * HH + jrow)) * KEYS + key0 + 32 * kt + lane31] =
            f2bf(accV[kt][reg] + bvr[reg]);
      }
    }
  }
}

// ---------------- pass A: online softmax stats + ssq (MFMA) ----------------
// 1024 blocks, 128 thr. XCD-swizzled: tq-siblings of (b,ks) share an XCD.
__global__ __launch_bounds__(128, 2) void passA_kernel(
    const ushort_t* __restrict__ q_hi, const ushort_t* __restrict__ q_lo,
    const ushort_t* __restrict__ k_hi, const ushort_t* __restrict__ k_lo,
    float* __restrict__ m_part, float* __restrict__ l_part,
    float* __restrict__ ssq_part)
{
  __shared__ ushort_t Khi[64 * LDK];
  __shared__ ushort_t Klo[64 * LDK];
  const int tid = threadIdx.x, l = tid & 63, w = tid >> 6;
  const int g = (l >> 5) & 1, lane31 = l & 31;
  const int p = blockIdx.x;
  const int xcd = p & 7, slot = p >> 3;          // slot 0..127
  const int pair = xcd * 32 + (slot >> 2);       // 0..255
  const int tq = slot & 3;
  const int b = pair >> 2, ks = pair & 3;
  const int t0 = tq * 64;

  bf16x8 qhi[8], qlo[8];
  {
    const long qb = ((long)(b * TT + t0 + 32 * w + lane31)) * HH;
    #pragma unroll
    for (int hs = 0; hs < 8; ++hs) {
      qhi[hs] = *reinterpret_cast<const bf16x8*>(q_hi + qb + 16 * hs + 8 * g);
      qlo[hs] = *reinterpret_cast<const bf16x8*>(q_lo + qb + 16 * hs + 8 * g);
    }
  }

  float mreg[16], lreg[16], ssq = 0.f;
  #pragma unroll
  for (int r = 0; r < 16; ++r) { mreg[r] = -1e30f; lreg[r] = 0.f; }

  for (int kt = 0; kt < 16; ++kt) {
    const int kb = ks * 1024 + kt * 64;
    __syncthreads();
    #pragma unroll
    for (int i = 0; i < 8; ++i) {
      int slot2 = i * 128 + tid;                 // 0..1023
      int row = slot2 >> 4, c0 = (slot2 & 15) << 3;
      const long gsrc = ((long)(b * KEYS + kb + row)) * HH + c0;
      *reinterpret_cast<uint4*>(&Khi[row * LDK + c0]) =
          *reinterpret_cast<const uint4*>(k_hi + gsrc);
      *reinterpret_cast<uint4*>(&Klo[row * LDK + c0]) =
          *reinterpret_cast<const uint4*>(k_lo + gsrc);
    }
    __syncthreads();

    f32x16 acc0 = zero16(), acc1 = zero16();
    #pragma unroll
    for (int hs = 0; hs < 8; ++hs) {
      const int ho = 16 * hs + 8 * g;
      bf16x8 kh0 = *reinterpret_cast<const bf16x8*>(&Khi[lane31 * LDK + ho]);
      bf16x8 kl0 = *reinterpret_cast<const bf16x8*>(&Klo[lane31 * LDK + ho]);
      bf16x8 kh1 = *reinterpret_cast<const bf16x8*>(&Khi[(32 + lane31) * LDK + ho]);
      bf16x8 kl1 = *reinterpret_cast<const bf16x8*>(&Klo[(32 + lane31) * LDK + ho]);
      acc0 = mfma3(qhi[hs], qlo[hs], kh0, kl0, acc0);
      acc1 = mfma3(qhi[hs], qlo[hs], kh1, kl1, acc1);
    }

    const int st0 = (kb + lane31) & 255;
    const int st1 = (kb + 32 + lane31) & 255;
    #pragma unroll
    for (int reg = 0; reg < 16; ++reg) {
      const int tr = t0 + 32 * w + (reg & 3) + 8 * (reg >> 2) + 4 * g;
      float s0 = acc0[reg], s1 = acc1[reg];
      ssq = fmaf(s0, s0, fmaf(s1, s1, ssq));
      bool msk0 = st0 > tr, msk1 = st1 > tr;
      float v0 = msk0 ? -1e30f : s0;
      float v1 = msk1 ? -1e30f : s1;
      float mn = fmaxf(mreg[reg], fmaxf(v0, v1));
      float sc = __expf(mreg[reg] - mn);
      float p0 = msk0 ? 0.f : __expf(s0 - mn);
      float p1 = msk1 ? 0.f : __expf(s1 - mn);
      lreg[reg] = fmaf(lreg[reg], sc, p0 + p1);
      mreg[reg] = mn;
    }
  }

  #pragma unroll
  for (int reg = 0; reg < 16; ++reg) {
    #pragma unroll
    for (int off = 1; off < 32; off <<= 1) {
      float mo = __shfl_xor(mreg[reg], off);
      float lo = __shfl_xor(lreg[reg], off);
      float mn = fmaxf(mreg[reg], mo);
      lreg[reg] = lreg[reg] * __expf(mreg[reg] - mn) + lo * __expf(mo - mn);
      mreg[reg] = mn;
    }
  }
  if (lane31 == 0) {
    #pragma unroll
    for (int reg = 0; reg < 16; ++reg) {
      const int tr = t0 + 32 * w + (reg & 3) + 8 * (reg >> 2) + 4 * g;
      m_part[ks * (BB * TT) + b * TT + tr] = mreg[reg];
      l_part[ks * (BB * TT) + b * TT + tr] = lreg[reg];
    }
  }
  #pragma unroll
  for (int off = 1; off < 64; off <<= 1) ssq += __shfl_xor(ssq, off);
  __syncthreads();
  float* red = reinterpret_cast<float*>(Khi);
  if (l == 0) red[w] = ssq;
  __syncthreads();
  if (tid == 0) ssq_part[b * 16 + tq * 4 + ks] = red[0] + red[1];
}

__global__ void merge_ml_kernel(const float* __restrict__ m_part,
                                const float* __restrict__ l_part,
                                float* __restrict__ m_ws,
                                float* __restrict__ l_ws)
{
  int idx = blockIdx.x * 256 + threadIdx.x;
  if (idx >= BB * TT) return;
  float m = -1e30f;
  #pragma unroll
  for (int k = 0; k < 4; ++k) m = fmaxf(m, m_part[k * (BB * TT) + idx]);
  float lsum = 0.f;
  #pragma unroll
  for (int k = 0; k < 4; ++k)
    lsum += l_part[k * (BB * TT) + idx] * __expf(m_part[k * (BB * TT) + idx] - m);
  m_ws[idx] = m;
  l_ws[idx] = lsum;
}

// ---------------- pass B: recompute S, write A, O += A*V (MFMA) ------------
// 512 blocks, 256 thr. XCD-swizzled: tq-siblings of (b,ksb) share an XCD.
__global__ __launch_bounds__(256, 2) void passB_kernel(
    const ushort_t* __restrict__ q_hi, const ushort_t* __restrict__ q_lo,
    const ushort_t* __restrict__ k_hi, const ushort_t* __restrict__ k_lo,
    const ushort_t* __restrict__ v_t,
    const float* __restrict__ m_ws, const float* __restrict__ l_ws,
    float* __restrict__ A_out, float* __restrict__ opart)
{
  __shared__ ushort_t Khi[64 * LDK];
  __shared__ ushort_t Klo[64 * LDK];
  __shared__ ushort_t Vt[128 * LDV];
  __shared__ ushort_t As[64 * LDV];
  const int tid = threadIdx.x, l = tid & 63, w = tid >> 6;
  const int g = (l >> 5) & 1, lane31 = l & 31;
  const int wt = w & 1, wk = w >> 1;
  const int p = blockIdx.x;
  const int xcd = p & 7, slot = p >> 3;          // slot 0..63
  const int pair = xcd * 16 + (slot >> 2);       // 0..127
  const int tq = slot & 3;
  const int b = pair >> 1, ksb = pair & 1;
  const int t0 = tq * 64;

  bf16x8 qhi[8], qlo[8];
  {
    const long qb = ((long)(b * TT + t0 + 32 * wt + lane31)) * HH;
    #pragma unroll
    for (int hs = 0; hs < 8; ++hs) {
      qhi[hs] = *reinterpret_cast<const bf16x8*>(q_hi + qb + 16 * hs + 8 * g);
      qlo[hs] = *reinterpret_cast<const bf16x8*>(q_lo + qb + 16 * hs + 8 * g);
    }
  }
  float mreg[16], rinv[16];
  #pragma unroll
  for (int reg = 0; reg < 16; ++reg) {
    const int tr = t0 + 32 * wt + (reg & 3) + 8 * (reg >> 2) + 4 * g;
    mreg[reg] = m_ws[b * TT + tr];
    rinv[reg] = 1.0f / l_ws[b * TT + tr];
  }
  f32x16 o0 = zero16(), o1 = zero16();

  for (int kt = 0; kt < 32; ++kt) {
    const int kb = ksb * 2048 + kt * 64;
    __syncthreads();
    #pragma unroll
    for (int i = 0; i < 4; ++i) {
      int slot2 = i * 256 + tid;                 // 0..1023
      int row = slot2 >> 4, c0 = (slot2 & 15) << 3;
      const long gsrc = ((long)(b * KEYS + kb + row)) * HH + c0;
      *reinterpret_cast<uint4*>(&Khi[row * LDK + c0]) =
          *reinterpret_cast<const uint4*>(k_hi + gsrc);
      *reinterpret_cast<uint4*>(&Klo[row * LDK + c0]) =
          *reinterpret_cast<const uint4*>(k_lo + gsrc);
    }
    #pragma unroll
    for (int i = 0; i < 4; ++i) {
      int slot2 = i * 256 + tid;
      int hh = slot2 >> 3, k0 = (slot2 & 7) << 3;
      *reinterpret_cast<uint4*>(&Vt[hh * LDV + k0]) =
          *reinterpret_cast<const uint4*>(
              v_t + ((long)(b * HH + hh)) * KEYS + kb + k0);
    }
    __syncthreads();

    f32x16 acc = zero16();
    #pragma unroll
    for (int hs = 0; hs < 8; ++hs) {
      const int ho = 16 * hs + 8 * g;
      bf16x8 kh = *reinterpret_cast<const bf16x8*>(
          &Khi[(32 * wk + lane31) * LDK + ho]);
      bf16x8 kl = *reinterpret_cast<const bf16x8*>(
          &Klo[(32 * wk + lane31) * LDK + ho]);
      acc = mfma3(qhi[hs], qlo[hs], kh, kl, acc);
    }

    const int key = kb + 32 * wk + lane31;
    const int st = key & 255;
    #pragma unroll
    for (int reg = 0; reg < 16; ++reg) {
      const int rl = 32 * wt + (reg & 3) + 8 * (reg >> 2) + 4 * g;
      const int tr = t0 + rl;
      float a = (st <= tr) ? __expf(acc[reg] - mreg[reg]) * rinv[reg] : 0.f;
      A_out[((long)(b * TT + tr)) * KEYS + key] = a;
      As[rl * LDV + 32 * wk + lane31] = f2bf(a);
    }
    __syncthreads();

    #pragma unroll
    for (int ksx = 0; ksx < 4; ++ksx) {
      const int ko = 16 * ksx + 8 * g;
      bf16x8 af = *reinterpret_cast<const bf16x8*>(
          &As[(32 * wt + lane31) * LDV + ko]);
      bf16x8 v0 = *reinterpret_cast<const bf16x8*>(
          &Vt[(64 * wk + lane31) * LDV + ko]);
      bf16x8 v1 = *reinterpret_cast<const bf16x8*>(
          &Vt[(64 * wk + 32 + lane31) * LDV + ko]);
      o0 = __builtin_amdgcn_mfma_f32_32x32x16_bf16(af, v0, o0, 0, 0, 0);
      o1 = __builtin_amdgcn_mfma_f32_32x32x16_bf16(af, v1, o1, 0, 0, 0);
    }
  }

  #pragma unroll
  for (int reg = 0; reg < 16; ++reg) {
    const int tr = t0 + 32 * wt + (reg & 3) + 8 * (reg >> 2) + 4 * g;
    long base = (long)ksb * (BB * TT * HH) + ((long)(b * TT + tr)) * HH + 64 * wk;
    opart[base + lane31]      = o0[reg];
    opart[base + 32 + lane31] = o1[reg];
  }
}

__global__ void reduce_out_kernel(const float* __restrict__ opart,
                                  float* __restrict__ out)
{
  int i = blockIdx.x * 256 + threadIdx.x;
  const int n4 = BB * TT * HH / 4;
  if (i >= n4) return;
  const float4* p0 = reinterpret_cast<const float4*>(opart);
  const float4* p1 = reinterpret_cast<const float4*>(opart + BB * TT * HH);
  float4 a = p0[i], c = p1[i];
  a.x += c.x; a.y += c.y; a.z += c.z; a.w += c.w;
  *reinterpret_cast<float4*>(out + 4 * (long)i) = a;
}

__global__ void finalize_kernel(const float* __restrict__ ssq_part,
                                float* __restrict__ S_norm)
{
  int b = threadIdx.x;
  if (b < BB) {
    float s = 0.f;
    #pragma unroll
    for (int i = 0; i < 16; ++i) s += ssq_part[b * 16 + i];
    S_norm[b] = sqrtf(s);
  }
}

extern "C" void kernel_launch(void* const* d_in, const int* in_sizes, int n_in,
                              void* d_out, int out_size, void* d_ws, size_t ws_size,
                              hipStream_t stream)
{
  const float* node  = (const float*)d_in[0];
  const float* neigh = (const float*)d_in[1];
  const float* Wq = (const float*)d_in[4];
  const float* bq = (const float*)d_in[5];
  const float* Wk = (const float*)d_in[6];
  const float* bk = (const float*)d_in[7];
  const float* Wv = (const float*)d_in[8];
  const float* bv = (const float*)d_in[9];

  float* out    = (float*)d_out;
  float* A_out  = out + (long)BB * TT * HH;
  float* S_norm = A_out + (long)BB * TT * KEYS;

  ushort_t* q_hi = (ushort_t*)d_ws;                      // B*T*H
  ushort_t* q_lo = q_hi + (long)BB * TT * HH;
  ushort_t* k_hi = q_lo + (long)BB * TT * HH;            // B*KEYS*H
  ushort_t* k_lo = k_hi + (long)BB * KEYS * HH;
  ushort_t* v_t  = k_lo + (long)BB * KEYS * HH;          // B*H*KEYS
  ushort_t* wqh  = v_t + (long)BB * HH * KEYS;           // H*H x6
  ushort_t* wql  = wqh + HH * HH;
  ushort_t* wkh  = wql + HH * HH;
  ushort_t* wkl  = wkh + HH * HH;
  ushort_t* wvh  = wkl + HH * HH;
  ushort_t* wvl  = wvh + HH * HH;
  float* m_part = (float*)(wvl + HH * HH);               // 4*B*T
  float* l_part = m_part + 4 * BB * TT;
  float* ssq_part = l_part + 4 * BB * TT;                // 1024
  float* opart = ssq_part + 1024;                        // 2*B*T*H
  float* m_ws  = opart + 2L * BB * TT * HH;              // B*T
  float* l_ws  = m_ws + BB * TT;

  prep_w_kernel<<<dim3((HH * HH + 255) / 256), dim3(256), 0, stream>>>(
      Wq, Wk, Wv, wqh, wql, wkh, wkl, wvh, wvl);
  proj_kernel<false><<<dim3(BB * TT / 128), dim3(256), 0, stream>>>(
      node, neigh, wqh, wql, bq, wvh, wvl, bv, q_hi, q_lo, v_t, 0);
  proj_kernel<true><<<dim3(BB * KEYS / 128), dim3(256), 0, stream>>>(
      node, neigh, wkh, wkl, bk, wvh, wvl, bv, k_hi, k_lo, v_t, 1);
  passA_kernel<<<dim3(BB * 16), dim3(128), 0, stream>>>(
      q_hi, q_lo, k_hi, k_lo, m_part, l_part, ssq_part);
  merge_ml_kernel<<<dim3((BB * TT + 255) / 256), dim3(256), 0, stream>>>(
      m_part, l_part, m_ws, l_ws);
  passB_kernel<<<dim3(BB * 8), dim3(256), 0, stream>>>(
      q_hi, q_lo, k_hi, k_lo, v_t, m_ws, l_ws, A_out, opart);
  reduce_out_kernel<<<dim3((BB * TT * HH / 4 + 255) / 256), dim3(256), 0, stream>>>(
      opart, out);
  finalize_kernel<<<dim3(1), dim3(64), 0, stream>>>(ssq_part, S_norm);
}